// Round 3
// baseline (342.661 us; speedup 1.0000x reference)
//
#include <hip/hip_runtime.h>
#include <math.h>

// ---------------------------------------------------------------------------
// MegaCartTensorOut: fused equivariant TP block.
//
// CG table layout in d_ws (floats):
//   i0 (0,0,0) off 0   sz 1
//   i1 (1,1,0) off 1   sz 9
//   i2 (2,2,0) off 10  sz 25
//   i3 (1,1,1) off 35  sz 27
//   i4 (2,2,1) off 62  sz 75
//   i5 (0,2,2) off 137 sz 25
//   i6 (2,0,2) off 162 sz 25
//   i7 (1,1,2) off 187 sz 45
//   i8 (2,2,2) off 232 sz 125   (end 357)
//   QB0 off 357 sz 9, QB1 off 366 sz 27, QB2 off 393 sz 45  -> total 438
// ---------------------------------------------------------------------------

#define N_CG_FLOATS 438

__device__ __forceinline__ double dfact(int n) {
  double r = 1.0;
  for (int i = 2; i <= n; ++i) r *= (double)i;
  return r;
}

// U[l] element (row i = real m, col j = complex m): re + i*im
__device__ __forceinline__ void u_elem(int l, int i, int j, double& re, double& im) {
  re = 0.0; im = 0.0;
  const int mr = i - l, mc = j - l;
  const double is2 = 0.70710678118654752440;
  if (mr == 0) {
    if (mc == 0) re = 1.0;
  } else if (mr > 0) {
    if (mc == mr) re = ((mr & 1) ? -1.0 : 1.0) * is2;
    else if (mc == -mr) re = is2;
  } else {
    int m = -mr;
    if (mc == m) im = -(((m & 1) ? -1.0 : 1.0)) * is2;
    else if (mc == -m) im = is2;
  }
}

// One block per tensor; parallel over elements. Exact math of the reference.
__global__ void setup_cg_par(float* __restrict__ ws) {
  const int LAs[12] = {0, 1, 2, 1, 2, 0, 2, 1, 2, 1, 1, 1};
  const int LBs[12] = {0, 1, 2, 1, 2, 2, 0, 1, 2, 1, 1, 1};
  const int LOs[12] = {0, 0, 0, 1, 1, 2, 2, 2, 2, 0, 1, 2};
  const int OFF[12] = {0, 1, 10, 35, 62, 137, 162, 187, 232, 357, 366, 393};

  const int blk = blockIdx.x;
  const int l1 = LAs[blk], l2 = LBs[blk], l3 = LOs[blk];
  const double scale = (blk >= 9) ? sqrt(2.0 * l3 + 1.0) : 1.0;
  const int n1 = 2 * l1 + 1, n2 = 2 * l2 + 1, n3 = 2 * l3 + 1;
  const int nel = n1 * n2 * n3;
  const int t = threadIdx.x;

  __shared__ double Cs[125];
  __shared__ double Rre[125], Rim[125];
  __shared__ double s_inv;
  __shared__ int s_useRe;

  if (t < nel) {
    const int i3 = t % n3, i2 = (t / n3) % n2, i1 = t / (n3 * n2);
    const int m1 = i1 - l1, m2 = i2 - l2, m3 = i3 - l3;
    double val = 0.0;
    if (m1 + m2 == m3) {
      double pre = sqrt((2.0 * l3 + 1.0) * dfact(l1 + l2 - l3) * dfact(l1 - l2 + l3) *
                        dfact(-l1 + l2 + l3) / dfact(l1 + l2 + l3 + 1));
      pre *= sqrt(dfact(l3 + m3) * dfact(l3 - m3) * dfact(l1 - m1) * dfact(l1 + m1) *
                  dfact(l2 - m2) * dfact(l2 + m2));
      double s = 0.0;
      for (int k = 0; k <= l1 + l2 - l3; ++k) {
        int d1 = l1 + l2 - l3 - k, d2 = l1 - m1 - k, d3 = l2 + m2 - k;
        int d4 = l3 - l2 + m1 + k, d5 = l3 - l1 - m2 + k;
        if (d1 < 0 || d2 < 0 || d3 < 0 || d4 < 0 || d5 < 0) continue;
        double prod = dfact(k) * dfact(d1) * dfact(d2) * dfact(d3) * dfact(d4) * dfact(d5);
        s += ((k & 1) ? -1.0 : 1.0) / prod;
      }
      val = pre * s;
    }
    Cs[t] = val;
  }
  __syncthreads();

  if (t < nel) {
    const int c = t % n3, bb = (t / n3) % n2, a = t / (n3 * n2);
    double sr_ = 0.0, si_ = 0.0;
    for (int m = 0; m < n1; ++m) {
      double u1r, u1i;
      u_elem(l1, a, m, u1r, u1i);
      if (u1r == 0.0 && u1i == 0.0) continue;
      for (int nn = 0; nn < n2; ++nn) {
        double u2r, u2i;
        u_elem(l2, bb, nn, u2r, u2i);
        double t12r = u1r * u2r - u1i * u2i;
        double t12i = u1r * u2i + u1i * u2r;
        if (t12r == 0.0 && t12i == 0.0) continue;
        for (int o = 0; o < n3; ++o) {
          double cgv = Cs[(m * n2 + nn) * n3 + o];
          if (cgv == 0.0) continue;
          double u3r, u3i;
          u_elem(l3, c, o, u3r, u3i);
          sr_ += (t12r * u3r + t12i * u3i) * cgv;
          si_ += (t12i * u3r - t12r * u3i) * cgv;
        }
      }
    }
    Rre[t] = sr_;
    Rim[t] = si_;
  }
  __syncthreads();

  if (t == 0) {
    double maxRe = 0.0, maxIm = 0.0;
    for (int e = 0; e < nel; ++e) {
      maxRe = fmax(maxRe, fabs(Rre[e]));
      maxIm = fmax(maxIm, fabs(Rim[e]));
    }
    int useRe = (maxRe >= maxIm) ? 1 : 0;
    double nrm = 0.0;
    for (int e = 0; e < nel; ++e) {
      double vv = useRe ? Rre[e] : Rim[e];
      nrm += vv * vv;
    }
    s_useRe = useRe;
    s_inv = scale / sqrt(nrm);
  }
  __syncthreads();

  if (t < nel) {
    double vv = s_useRe ? Rre[t] : Rim[t];
    ws[OFF[blk] + t] = (float)(vv * s_inv);
  }
}

// ---------------------------------------------------------------------------

template <int LA, int LB, int LO>
__device__ __forceinline__ void tp_accum(const float* __restrict__ R, float w,
                                         const float* xa, const float* xb, float* sph) {
  constexpr int NA = 2 * LA + 1, NB = 2 * LB + 1, NC = 2 * LO + 1;
#pragma unroll
  for (int a = 0; a < NA; ++a) {
#pragma unroll
    for (int b = 0; b < NB; ++b) {
      float xab = xa[a] * xb[b] * w;
#pragma unroll
      for (int c = 0; c < NC; ++c) sph[c] = fmaf(xab, R[(a * NB + b) * NC + c], sph[c]);
    }
  }
}

#define ELT(vec, e) (((const float*)&(vec))[e])

__global__ __launch_bounds__(256) void mega_node_kernel(
    const float* __restrict__ x_scalar, const float* __restrict__ x_sph,
    const int* __restrict__ batch, const float* __restrict__ W0, const float* __restrict__ W1,
    const float* __restrict__ W2, const float* __restrict__ A1, const float* __restrict__ b1,
    const float* __restrict__ A2, const float* __restrict__ b2, const float* __restrict__ p0,
    const float* __restrict__ p1, const float* __restrict__ p2, const float* __restrict__ cg_g,
    float* __restrict__ out, int N) {
  __shared__ __align__(16) float cg[N_CG_FLOATS];
  __shared__ __align__(16) float xs_lds[16 * 128];
  __shared__ __align__(16) float sp_lds[16 * 480];
  __shared__ __align__(16) float h_lds[16][64];

  const int t = threadIdx.x;
  const int b0 = blockIdx.x * 16;
  const int nb = min(16, N - b0);

  for (int i = t; i < N_CG_FLOATS; i += 256) cg[i] = cg_g[i];
  {
    const float4* src = (const float4*)(x_scalar + (long)b0 * 128);
    float4* dst = (float4*)xs_lds;
    const int nf = nb * 32;
    for (int i = t; i < nf; i += 256) dst[i] = src[i];
    const float4* s2 = (const float4*)(x_sph + (long)b0 * 480);
    float4* d2 = (float4*)sp_lds;
    const int nf2 = nb * 120;
    for (int i = t; i < nf2; i += 256) d2[i] = s2[i];
  }
  __syncthreads();

  const int v = t & 31;
  const int sl = t >> 5;                 // 0..7
  const bool actA = (sl < nb);           // node A = b0 + sl
  const bool actB = (sl + 8 < nb);       // node B = b0 + sl + 8
  const int rA = actA ? sl : 0;
  const int rB = actB ? (sl + 8) : 0;

  // ---- h = silu(x_scalar @ A1 + b1), 2 cols per lane, 2 nodes per lane
  {
    const float4* xA4 = (const float4*)(xs_lds + rA * 128);
    const float4* xB4 = (const float4*)(xs_lds + rB * 128);
    float hA0 = b1[v], hA1 = b1[v + 32];
    float hB0 = hA0, hB1 = hA1;
#pragma unroll 4
    for (int q = 0; q < 32; ++q) {
      float4 a = xA4[q], b = xB4[q];
#pragma unroll
      for (int e = 0; e < 4; ++e) {
        const int j = q * 4 + e;
        float w0 = A1[j * 64 + v], w1 = A1[j * 64 + v + 32];
        float ae = ELT(a, e), be = ELT(b, e);
        hA0 = fmaf(ae, w0, hA0); hA1 = fmaf(ae, w1, hA1);
        hB0 = fmaf(be, w0, hB0); hB1 = fmaf(be, w1, hB1);
      }
    }
    h_lds[sl][v]          = hA0 / (1.0f + __expf(-hA0));
    h_lds[sl][v + 32]     = hA1 / (1.0f + __expf(-hA1));
    h_lds[sl + 8][v]      = hB0 / (1.0f + __expf(-hB0));
    h_lds[sl + 8][v + 32] = hB1 / (1.0f + __expf(-hB1));
  }
  __syncthreads();

  // ---- channel mixes (out channel = v) for both nodes
  const float4* sA4 = (const float4*)(sp_lds + rA * 480);
  const float4* sB4 = (const float4*)(sp_lds + rB * 480);

  float y0A = 0.f, y0B = 0.f;
#pragma unroll 4
  for (int q = 0; q < 32; ++q) {
    float4 a = sA4[q], b = sB4[q];
#pragma unroll
    for (int e = 0; e < 4; ++e) {
      float w = W0[(q * 4 + e) * 32 + v];
      y0A = fmaf(ELT(a, e), w, y0A);
      y0B = fmaf(ELT(b, e), w, y0B);
    }
  }
  y0A *= 0.08838834764831845f;
  y0B *= 0.08838834764831845f;

  float y1A[3] = {0.f, 0.f, 0.f}, y1B[3] = {0.f, 0.f, 0.f};
#pragma unroll 4
  for (int q = 0; q < 16; ++q) {  // 12 elems (4 u's) per chunk
    float4 a0 = sA4[32 + q * 3], a1 = sA4[32 + q * 3 + 1], a2 = sA4[32 + q * 3 + 2];
    float4 c0 = sB4[32 + q * 3], c1 = sB4[32 + q * 3 + 1], c2 = sB4[32 + q * 3 + 2];
    float eA[12] = {a0.x, a0.y, a0.z, a0.w, a1.x, a1.y, a1.z, a1.w, a2.x, a2.y, a2.z, a2.w};
    float eB[12] = {c0.x, c0.y, c0.z, c0.w, c1.x, c1.y, c1.z, c1.w, c2.x, c2.y, c2.z, c2.w};
    float w = 0.f;
#pragma unroll
    for (int e = 0; e < 12; ++e) {
      if (e % 3 == 0) w = W1[(q * 4 + e / 3) * 32 + v];
      y1A[e % 3] = fmaf(eA[e], w, y1A[e % 3]);
      y1B[e % 3] = fmaf(eB[e], w, y1B[e % 3]);
    }
  }
#pragma unroll
  for (int m = 0; m < 3; ++m) { y1A[m] *= 0.125f; y1B[m] *= 0.125f; }

  float y2A[5] = {0.f, 0.f, 0.f, 0.f, 0.f}, y2B[5] = {0.f, 0.f, 0.f, 0.f, 0.f};
#pragma unroll 2
  for (int q = 0; q < 8; ++q) {  // 20 elems (4 u's) per chunk
    float4 a0 = sA4[80 + q * 5], a1 = sA4[80 + q * 5 + 1], a2 = sA4[80 + q * 5 + 2],
           a3 = sA4[80 + q * 5 + 3], a4 = sA4[80 + q * 5 + 4];
    float4 c0 = sB4[80 + q * 5], c1 = sB4[80 + q * 5 + 1], c2 = sB4[80 + q * 5 + 2],
           c3 = sB4[80 + q * 5 + 3], c4 = sB4[80 + q * 5 + 4];
    float eA[20] = {a0.x, a0.y, a0.z, a0.w, a1.x, a1.y, a1.z, a1.w, a2.x, a2.y,
                    a2.z, a2.w, a3.x, a3.y, a3.z, a3.w, a4.x, a4.y, a4.z, a4.w};
    float eB[20] = {c0.x, c0.y, c0.z, c0.w, c1.x, c1.y, c1.z, c1.w, c2.x, c2.y,
                    c2.z, c2.w, c3.x, c3.y, c3.z, c3.w, c4.x, c4.y, c4.z, c4.w};
    float w = 0.f;
#pragma unroll
    for (int e = 0; e < 20; ++e) {
      if (e % 5 == 0) w = W2[(q * 4 + e / 5) * 32 + v];
      y2A[e % 5] = fmaf(eA[e], w, y2A[e % 5]);
      y2B[e % 5] = fmaf(eB[e], w, y2B[e % 5]);
    }
  }
#pragma unroll
  for (int m = 0; m < 5; ++m) { y2A[m] *= 0.17677669529663687f; y2B[m] *= 0.17677669529663687f; }

  // ---- RMS norms (reduce over the 32 v-lanes of this half-wave)
  float s0A = y0A * y0A, s0B = y0B * y0B;
  float s1A = y1A[0] * y1A[0] + y1A[1] * y1A[1] + y1A[2] * y1A[2];
  float s1B = y1B[0] * y1B[0] + y1B[1] * y1B[1] + y1B[2] * y1B[2];
  float s2A = 0.f, s2B = 0.f;
#pragma unroll
  for (int m = 0; m < 5; ++m) { s2A = fmaf(y2A[m], y2A[m], s2A); s2B = fmaf(y2B[m], y2B[m], s2B); }
#pragma unroll
  for (int msk = 16; msk >= 1; msk >>= 1) {
    s0A += __shfl_xor(s0A, msk); s0B += __shfl_xor(s0B, msk);
    s1A += __shfl_xor(s1A, msk); s1B += __shfl_xor(s1B, msk);
    s2A += __shfl_xor(s2A, msk); s2B += __shfl_xor(s2B, msk);
  }
  const float i0A = 1.0f / sqrtf(s0A * (1.0f / 32.0f) + 1e-5f);
  const float i0B = 1.0f / sqrtf(s0B * (1.0f / 32.0f) + 1e-5f);
  const float i1A = 1.0f / sqrtf(s1A * (1.0f / 96.0f) + 1e-5f);
  const float i1B = 1.0f / sqrtf(s1B * (1.0f / 96.0f) + 1e-5f);
  const float i2A = 1.0f / sqrtf(s2A * (1.0f / 160.0f) + 1e-5f);
  const float i2B = 1.0f / sqrtf(s2B * (1.0f / 160.0f) + 1e-5f);

  float xs0A[1] = {y0A * i0A}, xs0B[1] = {y0B * i0B};
  float xs1A[3], xs1B[3], xs2A[5], xs2B[5];
#pragma unroll
  for (int m = 0; m < 3; ++m) { xs1A[m] = y1A[m] * i1A; xs1B[m] = y1B[m] * i1B; }
#pragma unroll
  for (int m = 0; m < 5; ++m) { xs2A[m] = y2A[m] * i2A; xs2B[m] = y2B[m] * i2B; }

  // ---- TP weights: wv9 = h @ A2 + b2, both nodes share each A2 element
  float wA[9], wB[9];
#pragma unroll
  for (int i = 0; i < 9; ++i) { float bb = b2[i * 32 + v]; wA[i] = bb; wB[i] = bb; }
  {
    const float4* hA4 = (const float4*)h_lds[sl];
    const float4* hB4 = (const float4*)h_lds[sl + 8];
#pragma unroll 4
    for (int q = 0; q < 16; ++q) {
      float4 ha = hA4[q], hb = hB4[q];
#pragma unroll
      for (int e = 0; e < 4; ++e) {
        const float* arow = A2 + (q * 4 + e) * 288 + v;
        float hae = ELT(ha, e), hbe = ELT(hb, e);
#pragma unroll
        for (int i = 0; i < 9; ++i) {
          float w = arow[i * 32];
          wA[i] = fmaf(hae, w, wA[i]);
          wB[i] = fmaf(hbe, w, wB[i]);
        }
      }
    }
  }

  // ---- 9 TP instructions; coef folds alpha * p_path / sqrt(P)
  const float invs32 = 0.17677669529663687f;
  const float k0 = invs32 / 3.0f;
  const float k1 = 1.7320508075688772f * invs32 / 2.0f;
  const float k2 = 2.23606797749979f * invs32 / 4.0f;
  const float c0 = k0 * p0[0], c1 = k0 * p0[1], c2 = k0 * p0[2];
  const float c3 = k1 * p1[0], c4 = k1 * p1[1];
  const float c5 = k2 * p2[0], c6 = k2 * p2[1], c7 = k2 * p2[2], c8 = k2 * p2[3];

  float sph0A[1] = {0.f}, sph1A[3] = {0.f, 0.f, 0.f}, sph2A[5] = {0.f, 0.f, 0.f, 0.f, 0.f};
  float sph0B[1] = {0.f}, sph1B[3] = {0.f, 0.f, 0.f}, sph2B[5] = {0.f, 0.f, 0.f, 0.f, 0.f};

  tp_accum<0, 0, 0>(cg + 0,   wA[0] * c0, xs0A, xs0A, sph0A);
  tp_accum<0, 0, 0>(cg + 0,   wB[0] * c0, xs0B, xs0B, sph0B);
  tp_accum<1, 1, 0>(cg + 1,   wA[1] * c1, xs1A, xs1A, sph0A);
  tp_accum<1, 1, 0>(cg + 1,   wB[1] * c1, xs1B, xs1B, sph0B);
  tp_accum<2, 2, 0>(cg + 10,  wA[2] * c2, xs2A, xs2A, sph0A);
  tp_accum<2, 2, 0>(cg + 10,  wB[2] * c2, xs2B, xs2B, sph0B);
  tp_accum<1, 1, 1>(cg + 35,  wA[3] * c3, xs1A, xs1A, sph1A);
  tp_accum<1, 1, 1>(cg + 35,  wB[3] * c3, xs1B, xs1B, sph1B);
  tp_accum<2, 2, 1>(cg + 62,  wA[4] * c4, xs2A, xs2A, sph1A);
  tp_accum<2, 2, 1>(cg + 62,  wB[4] * c4, xs2B, xs2B, sph1B);
  tp_accum<0, 2, 2>(cg + 137, wA[5] * c5, xs0A, xs2A, sph2A);
  tp_accum<0, 2, 2>(cg + 137, wB[5] * c5, xs0B, xs2B, sph2B);
  tp_accum<2, 0, 2>(cg + 162, wA[6] * c6, xs2A, xs0A, sph2A);
  tp_accum<2, 0, 2>(cg + 162, wB[6] * c6, xs2B, xs0B, sph2B);
  tp_accum<1, 1, 2>(cg + 187, wA[7] * c7, xs1A, xs1A, sph2A);
  tp_accum<1, 1, 2>(cg + 187, wB[7] * c7, xs1B, xs1B, sph2B);
  tp_accum<2, 2, 2>(cg + 232, wA[8] * c8, xs2A, xs2A, sph2A);
  tp_accum<2, 2, 2>(cg + 232, wB[8] * c8, xs2B, xs2B, sph2B);

  // ---- reduce sph over the 32 channel lanes
#pragma unroll
  for (int msk = 16; msk >= 1; msk >>= 1) {
    sph0A[0] += __shfl_xor(sph0A[0], msk);
    sph0B[0] += __shfl_xor(sph0B[0], msk);
#pragma unroll
    for (int m = 0; m < 3; ++m) {
      sph1A[m] += __shfl_xor(sph1A[m], msk);
      sph1B[m] += __shfl_xor(sph1B[m], msk);
    }
#pragma unroll
    for (int m = 0; m < 5; ++m) {
      sph2A[m] += __shfl_xor(sph2A[m], msk);
      sph2B[m] += __shfl_xor(sph2B[m], msk);
    }
  }

  // ---- cartesian transform + rolled segment-sum
  if (v == 0) {
    const float* qb0 = cg + 357;
    const float* qb1 = cg + 366;
    const float* qb2 = cg + 393;
#pragma unroll
    for (int nd = 0; nd < 2; ++nd) {
      const bool act = nd ? actB : actA;
      if (!act) continue;
      const int n = b0 + (nd ? (sl + 8) : sl);
      const float* s0p = nd ? sph0B : sph0A;
      const float* s1p = nd ? sph1B : sph1A;
      const float* s2p = nd ? sph2B : sph2A;
      float* og = out + (long)batch[n] * 9;
#pragma unroll
      for (int i = 0; i < 3; ++i) {
#pragma unroll
        for (int j = 0; j < 3; ++j) {
          float val = s0p[0] * qb0[i * 3 + j];
#pragma unroll
          for (int m = 0; m < 3; ++m) val = fmaf(s1p[m], qb1[(i * 3 + j) * 3 + m], val);
#pragma unroll
          for (int m = 0; m < 5; ++m) val = fmaf(s2p[m], qb2[(i * 3 + j) * 5 + m], val);
          atomicAdd(&og[((i + 1) % 3) * 3 + ((j + 1) % 3)], val);
        }
      }
    }
  }
}

// ---------------------------------------------------------------------------

extern "C" void kernel_launch(void* const* d_in, const int* in_sizes, int n_in,
                              void* d_out, int out_size, void* d_ws, size_t ws_size,
                              hipStream_t stream) {
  const float* x_scalar = (const float*)d_in[0];
  const float* x_sph    = (const float*)d_in[1];
  const int*   batch    = (const int*)d_in[2];
  const float* W0 = (const float*)d_in[4];
  const float* W1 = (const float*)d_in[5];
  const float* W2 = (const float*)d_in[6];
  const float* A1 = (const float*)d_in[7];
  const float* b1 = (const float*)d_in[8];
  const float* A2 = (const float*)d_in[9];
  const float* b2 = (const float*)d_in[10];
  const float* p0 = (const float*)d_in[11];
  const float* p1 = (const float*)d_in[12];
  const float* p2 = (const float*)d_in[13];
  float* out = (float*)d_out;
  float* ws  = (float*)d_ws;

  const int N = in_sizes[0] / 128;

  hipMemsetAsync(d_out, 0, (size_t)out_size * sizeof(float), stream);
  setup_cg_par<<<12, 128, 0, stream>>>(ws);
  const int blocks = (N + 15) / 16;
  mega_node_kernel<<<blocks, 256, 0, stream>>>(x_scalar, x_sph, batch, W0, W1, W2, A1, b1, A2,
                                               b2, p0, p1, p2, ws, out, N);
}